// Round 3
// baseline (98.854 us; speedup 1.0000x reference)
//
#include <hip/hip_runtime.h>
#include <cstdint>

// ---------------------------------------------------------------------------
// FP8 QDQ Conv2d:  out = conv2d(qdq_fp8(x,2), w*2, pad=1) + bias
//                = 4 * conv2d(fp8(x/2), fp8(w)) + bias     (exact in fp8)
// x: (32,128,56,56) f32 NCHW; w: (256,128,3,3) f32 (fp8-representable); b: (256,)
// out: (32,256,56,56) f32.  Implicit GEMM: M = 100352, N = 256, K = 9*128.
//
// R3: T3+T4 counted-vmcnt pipeline. BM=256 x BN=128, 512 thr (8 waves 4x2),
// BK=64 (18 K-steps), TRIPLE-buffered LDS (72KB -> 2 blocks/CU). Raw s_barrier
// + s_waitcnt vmcnt(3): prefetch 2 iters deep, loads in flight ACROSS barriers,
// vmcnt(0) only at the last iter. LDS = paired-M-rows [rp][128B], 16B XOR
// swizzle (linear g2l dest + inverse-swizzled global src, swizzled read).
// ---------------------------------------------------------------------------

#define NB   32
#define CIN  128
#define HW   56
#define KOUT 256
#define MTOT (32 * 56 * 56)                      // 100352

#define ACT_BYTES (32u * 56u * 56u * 128u)       // 12,845,056  NHWC fp8
#define WT_OFF    ACT_BYTES
#define WT_BYTES  (9u * 256u * 128u)             // 294,912     [rs][k][c] fp8

typedef float        f32x4 __attribute__((ext_vector_type(4)));
typedef unsigned int u32x4 __attribute__((ext_vector_type(4)));

// --------------------------- fp8 pack helpers ------------------------------
__device__ __forceinline__ unsigned int pack2_fp8(float a, float b) {
  a = fminf(fmaxf(a, -448.f), 448.f);
  b = fminf(fmaxf(b, -448.f), 448.f);
  return (unsigned int)__builtin_amdgcn_cvt_pk_fp8_f32(a, b, 0, false);
}

// ------------------- kernel 1: qdq + NCHW -> NHWC fp8 ----------------------
__global__ __launch_bounds__(256) void qdq_pack(const float* __restrict__ X,
                                                unsigned char* __restrict__ act) {
  const int nh = blockIdx.x;               // 0..1791
  const int n = nh / HW, h = nh - n * HW;
  const float* xb = X + (size_t)n * (CIN * HW * HW) + h * HW;  // + c*3136 + w
  unsigned char* ob = act + (size_t)nh * (HW * CIN);

  for (int i = 0; i < 2; ++i) {
    int item = threadIdx.x + i * 256;
    if (item >= HW * 8) break;             // 56 w * 8 c-groups of 16
    int w = item % HW, cg = item / HW;
    unsigned int dw[4];
#pragma unroll
    for (int jj = 0; jj < 4; ++jj) {
      int c0 = cg * 16 + jj * 4;
      float v0 = xb[(c0 + 0) * 3136 + w] * 0.5f;
      float v1 = xb[(c0 + 1) * 3136 + w] * 0.5f;
      float v2 = xb[(c0 + 2) * 3136 + w] * 0.5f;
      float v3 = xb[(c0 + 3) * 3136 + w] * 0.5f;
      unsigned int lo = pack2_fp8(v0, v1) & 0xffffu;
      unsigned int hi = pack2_fp8(v2, v3) & 0xffffu;
      dw[jj] = lo | (hi << 16);
    }
    u32x4 v = {dw[0], dw[1], dw[2], dw[3]};
    *(u32x4*)(ob + w * CIN + cg * 16) = v;
  }
}

// --------------- kernel 2: weight OIHW f32 -> [rs][k][c] fp8 ---------------
__global__ __launch_bounds__(256) void pack_weight(const float* __restrict__ W,
                                                   unsigned char* __restrict__ wt) {
  int gid = blockIdx.x * 256 + threadIdx.x;   // one dword (4 c) per thread
  int o = gid * 4;
  if (o >= (int)WT_BYTES) return;
  int rs = o >> 15;                // /32768 (= 256*128)
  int rem = o & 32767;
  int k  = rem >> 7;
  int c0 = rem & 127;
  float v0 = W[k * 1152 + (c0 + 0) * 9 + rs];
  float v1 = W[k * 1152 + (c0 + 1) * 9 + rs];
  float v2 = W[k * 1152 + (c0 + 2) * 9 + rs];
  float v3 = W[k * 1152 + (c0 + 3) * 9 + rs];
  unsigned int dw = (pack2_fp8(v0, v1) & 0xffffu) | (pack2_fp8(v2, v3) << 16);
  *(unsigned int*)(wt + o) = dw;
}

// ------------------------- kernel 3: implicit GEMM -------------------------
__device__ __forceinline__ void g2l16(const void* g, void* l) {
  __builtin_amdgcn_global_load_lds((const __attribute__((address_space(1))) void*)g,
                                   (__attribute__((address_space(3))) void*)l,
                                   16, 0, 0);
}

__global__ __launch_bounds__(512, 4) void conv_mfma(const unsigned char* __restrict__ act,
                                                    const unsigned char* __restrict__ wt,
                                                    const float* __restrict__ bias,
                                                    float* __restrict__ out) {
  // Triple-buffered. A: 256 M-rows x 64B (paired: [128 rp][128B]); B: 128 k x 64B
  // (paired: [64 rp][128B]). 16B slots XOR-swizzled by (rp&7).
  __shared__ __align__(16) unsigned char ldsA[3][16384];
  __shared__ __align__(16) unsigned char ldsB[3][8192];

  const int tid  = threadIdx.x;
  const int lane = tid & 63;
  const int wid  = tid >> 6;                   // 0..7
  const int wr   = wid >> 1, wc = wid & 1;     // 4x2 waves -> 64x64 out each

  // XCD-aware swizzle over 784 blocks (784 = 98*8, bijective).
  const int idx  = (int)blockIdx.x;
  const int nidx = (idx & 7) * 98 + (idx >> 3);
  const int bmi  = nidx % 392, bni = nidx / 392;
  const int bm   = bmi << 8;                   // 392 m-tiles of 256
  const int bn   = bni << 7;                   // 2 k-tiles of 128

  // per-fragment-row coords for pad masking
  int h_[4], w_[4];
#pragma unroll
  for (int mi = 0; mi < 4; ++mi) {
    int m = bm + (wr << 6) + (mi << 4) + (lane & 15);
    int hw = m % 3136;
    h_[mi] = hw / 56;
    w_[mi] = hw - 56 * (hw / 56);
  }

  auto stage = [&](int tt) {
    const int rs2 = tt >> 1;
    const int chalf = (tt & 1) << 6;
    const int r = rs2 / 3, s = rs2 - 3 * r;
    const int off = 56 * (r - 1) + (s - 1);
    unsigned char* bA = ldsA[tt % 3];
    unsigned char* bB = ldsB[tt % 3];
    const unsigned char* wseg = wt + (rs2 << 15) + chalf;
#pragma unroll
    for (int q = 0; q < 2; ++q) {              // A: 1024 16B chunks
      int c = tid + (q << 9);
      int rp = c >> 3, slot = c & 7;
      int sp = slot ^ (rp & 7);                // inverse swizzle on SOURCE
      int row = (rp << 1) + (sp >> 2);
      int kb = (sp & 3) << 4;
      int p = bm + row + off;
      p = p < 0 ? 0 : (p > MTOT - 1 ? MTOT - 1 : p);
      g2l16(act + ((size_t)p << 7) + chalf + kb, bA + (c << 4));
    }
    {                                          // B: 512 16B chunks
      int rp = tid >> 3, slot = tid & 7;
      int sp = slot ^ (rp & 7);
      int krow = (rp << 1) + (sp >> 2);
      int kb = (sp & 3) << 4;
      g2l16(wseg + ((size_t)(bn + krow) << 7) + kb, bB + (tid << 4));
    }
  };

  const f32x4 zero = {0.f, 0.f, 0.f, 0.f};
  f32x4 acc[4][4];
#pragma unroll
  for (int i = 0; i < 4; ++i)
#pragma unroll
    for (int j = 0; j < 4; ++j) acc[i][j] = zero;

  // swizzled-read helper: byte b within a 128B pair-row rp
  auto rdA = [&](const unsigned char* buf, int row, int b) -> long {
    int rp = row >> 1;
    int pb = ((row & 1) << 6) + b;
    return *(const long*)(buf + (rp << 7) + ((((pb >> 4) ^ (rp & 7)) << 4) | (pb & 15)));
  };

  stage(0);
  stage(1);

  for (int t = 0; t < 18; ++t) {
    if (t < 17) {
      asm volatile("s_waitcnt vmcnt(3)" ::: "memory");
    } else {
      asm volatile("s_waitcnt vmcnt(0)" ::: "memory");
    }
    __builtin_amdgcn_sched_barrier(0);
    __builtin_amdgcn_s_barrier();
    __builtin_amdgcn_sched_barrier(0);
    if (t < 16) stage(t + 2);                  // lands behind barrier t+2

    // ---- compute K-step t from buffers t%3 ----
    const int rs2 = t >> 1;
    const int r = rs2 / 3, s = rs2 - 3 * r;
    const unsigned char* bA = ldsA[t % 3];
    const unsigned char* bB = ldsB[t % 3];
    int vmask[4];
#pragma unroll
    for (int mi = 0; mi < 4; ++mi)
      vmask[mi] = (int)(((unsigned)(h_[mi] + r - 1) < 56u) &
                        ((unsigned)(w_[mi] + s - 1) < 56u));
    __builtin_amdgcn_s_setprio(1);
#pragma unroll
    for (int kk = 0; kk < 2; ++kk) {
      const int kbf = (kk << 5) + ((lane >> 4) << 3);
      long av[4], bv[4];
#pragma unroll
      for (int mi = 0; mi < 4; ++mi) {
        long v = rdA(bA, (wr << 6) + (mi << 4) + (lane & 15), kbf);
        av[mi] = vmask[mi] ? v : 0L;
      }
#pragma unroll
      for (int ni = 0; ni < 4; ++ni)
        bv[ni] = rdA(bB, (wc << 6) + (ni << 4) + (lane & 15), kbf);
#pragma unroll
      for (int mi = 0; mi < 4; ++mi)
#pragma unroll
        for (int ni = 0; ni < 4; ++ni)
          acc[mi][ni] = __builtin_amdgcn_mfma_f32_16x16x32_fp8_fp8(
              av[mi], bv[ni], acc[mi][ni], 0, 0, 0);
    }
    __builtin_amdgcn_s_setprio(0);
  }

  // epilogue: out[n][k][hw] = 4*acc + bias[k]; 4 consecutive m per lane = f32x4
#pragma unroll
  for (int ni = 0; ni < 4; ++ni) {
    int k = bn + (wc << 6) + (ni << 4) + (lane & 15);
    float bvv = bias[k];
#pragma unroll
    for (int mi = 0; mi < 4; ++mi) {
      int m = bm + (wr << 6) + (mi << 4) + ((lane >> 4) << 2);
      int n = m / 3136;
      int hw = m - n * 3136;
      f32x4 v = acc[mi][ni];
      v = v * 4.0f + bvv;
      *(f32x4*)(out + (size_t)(n * KOUT + k) * 3136 + hw) = v;
    }
  }
}

// ---------------------------------------------------------------------------
extern "C" void kernel_launch(void* const* d_in, const int* in_sizes, int n_in,
                              void* d_out, int out_size, void* d_ws, size_t ws_size,
                              hipStream_t stream) {
  const float* X = (const float*)d_in[0];
  const float* W = (const float*)d_in[1];
  const float* B = (const float*)d_in[2];
  float* out = (float*)d_out;

  unsigned char* act = (unsigned char*)d_ws;
  unsigned char* wtb = act + WT_OFF;

  hipLaunchKernelGGL(qdq_pack,    dim3(NB * HW), dim3(256), 0, stream, X, act);
  hipLaunchKernelGGL(pack_weight, dim3(288),     dim3(256), 0, stream, W, wtb);
  hipLaunchKernelGGL(conv_mfma,   dim3(784),     dim3(512), 0, stream, act, wtb, B,
                     out);
}